// Round 6
// baseline (1416.460 us; speedup 1.0000x reference)
//
#include <hip/hip_runtime.h>
#include <math.h>

#define NUM_LEVELS 16
#define N_DENSE 5
#define N_HASH (NUM_LEVELS - N_DENSE)
#define TABLE_SIZE (1u << 19)
#define TMASK (TABLE_SIZE - 1u)

typedef float f32x4 __attribute__((ext_vector_type(4)));
typedef short s16x8 __attribute__((ext_vector_type(8)));
typedef unsigned u32x2 __attribute__((ext_vector_type(2)));
typedef unsigned u32x4 __attribute__((ext_vector_type(4)));

struct HashParams { float scale[N_HASH]; };
struct DenseParams { float scale[N_DENSE]; unsigned res[N_DENSE]; };
struct AllParams { float scale[NUM_LEVELS]; unsigned res[NUM_LEVELS]; };

static __device__ __forceinline__ unsigned bf16_bits(float f) {
    const unsigned u = __builtin_bit_cast(unsigned, f);
    return (u + (0x7fffu + ((u >> 16) & 1u))) >> 16;
}
static __device__ __forceinline__ short bf16s(float f) { return (short)bf16_bits(f); }
static __device__ __forceinline__ float bflo(unsigned v) { return __builtin_bit_cast(float, v << 16); }
static __device__ __forceinline__ float bfhi(unsigned v) { return __builtin_bit_cast(float, v & 0xffff0000u); }

static __device__ __forceinline__ s16x8 packW8(const float* __restrict__ p) {
    const f32x4 a = *(const f32x4*)p;
    const f32x4 b = *(const f32x4*)(p + 4);
    s16x8 v;
    v[0] = bf16s(a.x); v[1] = bf16s(a.y); v[2] = bf16s(a.z); v[3] = bf16s(a.w);
    v[4] = bf16s(b.x); v[5] = bf16s(b.y); v[6] = bf16s(b.z); v[7] = bf16s(b.w);
    return v;
}
static __device__ __forceinline__ s16x8 packW8sig(const float* __restrict__ row, int q) {
    const f32x4 lo = *(const f32x4*)(row + 4 * q);
    const f32x4 hi = *(const f32x4*)(row + 16 + 4 * q);
    s16x8 v;
    v[0] = bf16s(lo.x); v[1] = bf16s(hi.x); v[2] = bf16s(lo.y); v[3] = bf16s(hi.y);
    v[4] = bf16s(lo.z); v[5] = bf16s(hi.z); v[6] = bf16s(lo.w); v[7] = bf16s(hi.w);
    return v;
}

// ---------------------------------------------------------------------------
// fp32 table -> packed bf16x2 table (1 dword/entry).
// ---------------------------------------------------------------------------
__global__ __launch_bounds__(256) void cvt_table_kernel(
    const f32x4* __restrict__ src, u32x2* __restrict__ dst, int n2)
{
    const int i = blockIdx.x * 256 + threadIdx.x;
    if (i >= n2) return;
    const f32x4 g = __builtin_nontemporal_load(src + i);
    u32x2 o;
    o.x = bf16_bits(g.x) | (bf16_bits(g.y) << 16);
    o.y = bf16_bits(g.z) | (bf16_bits(g.w) << 16);
    dst[i] = o;
}

// ---------------------------------------------------------------------------
// 11 hashed levels, level-major blocks, 2 points/thread, branchless.
// All 16 table loads issued before any consumption (MLP = 16/thread).
// ---------------------------------------------------------------------------
__global__ __launch_bounds__(256) void hashed_all_kernel(
    const float* __restrict__ texc,
    const unsigned* __restrict__ tb,   // bf16 tables
    unsigned* __restrict__ enc_ws,
    int n, int B2, HashParams P)
{
    __shared__ float tst[1536];
    const int tid = threadIdx.x;
    const unsigned lvl = blockIdx.x / (unsigned)B2;
    const unsigned blk = blockIdx.x - lvl * (unsigned)B2;
    const int i0 = (int)blk * 512;

#pragma unroll
    for (int j = 0; j < 6; ++j)
        tst[tid + 256 * j] = __builtin_nontemporal_load(texc + 3 * i0 + 256 * j + tid);
    __syncthreads();

    const float s = P.scale[lvl];
    const unsigned* tbl = tb + ((size_t)(N_DENSE + lvl) << 19);

    float wyzv[2][4], wxv[2][2];
    unsigned pA[2][4], pB[2][4], sA[2][4], sB[2][4];

#pragma unroll
    for (int pp = 0; pp < 2; ++pp) {
        const int t = tid + 256 * pp;
        const float tx = tst[3 * t], ty = tst[3 * t + 1], tz = tst[3 * t + 2];
        const float px = tx * s + 0.5f, py = ty * s + 0.5f, pz = tz * s + 0.5f;
        const float gx = floorf(px), gy = floorf(py), gz = floorf(pz);
        const float wx = px - gx, wy = py - gy, wz = pz - gz;
        const unsigned x0 = (unsigned)gx, y0 = (unsigned)gy, z0 = (unsigned)gz;
        const unsigned hy0 = y0 * 2654435761u, hy1 = (y0 + 1u) * 2654435761u;
        const unsigned hz0 = z0 * 805459861u,  hz1 = (z0 + 1u) * 805459861u;
        const unsigned hh[4] = { hy0 ^ hz0, hy1 ^ hz0, hy0 ^ hz1, hy1 ^ hz1 };
        wyzv[pp][0] = (1.f - wy) * (1.f - wz);
        wyzv[pp][1] = wy * (1.f - wz);
        wyzv[pp][2] = (1.f - wy) * wz;
        wyzv[pp][3] = wy * wz;
        wxv[pp][0] = 1.f - wx; wxv[pp][1] = wx;
#pragma unroll
        for (int c = 0; c < 4; ++c) {
            const unsigned ia = (x0 ^ hh[c]) & TMASK;
            const unsigned ib = ((x0 + 1u) ^ hh[c]) & TMASK;
            pA[pp][c] = ia & ~1u; sA[pp][c] = ia & 1u;
            pB[pp][c] = ib & ~1u; sB[pp][c] = ib & 1u;
        }
    }

    u32x2 gA[2][4], gB[2][4];
#pragma unroll
    for (int pp = 0; pp < 2; ++pp)
#pragma unroll
        for (int c = 0; c < 4; ++c) {
            gA[pp][c] = *(const u32x2*)(tbl + pA[pp][c]);
            gB[pp][c] = *(const u32x2*)(tbl + pB[pp][c]);
        }

#pragma unroll
    for (int pp = 0; pp < 2; ++pp) {
        float f0 = 0.f, f1 = 0.f;
#pragma unroll
        for (int c = 0; c < 4; ++c) {
            const unsigned ea = sA[pp][c] ? gA[pp][c].y : gA[pp][c].x;
            const unsigned eb = sB[pp][c] ? gB[pp][c].y : gB[pp][c].x;
            f0 += wyzv[pp][c] * (wxv[pp][0] * bflo(ea) + wxv[pp][1] * bflo(eb));
            f1 += wyzv[pp][c] * (wxv[pp][0] * bfhi(ea) + wxv[pp][1] * bfhi(eb));
        }
        const unsigned packed = bf16_bits(f0) | (bf16_bits(f1) << 16);
        __builtin_nontemporal_store(packed,
            enc_ws + (size_t)lvl * n + (i0 + tid + 256 * pp));
    }
}

// ---------------------------------------------------------------------------
// Dense levels (chunk-pipelined branchless gathers) + MFMA MLP.
// ---------------------------------------------------------------------------
__global__ __launch_bounds__(256) void dense_mlp_kernel(
    const float* __restrict__ texc,
    const unsigned* __restrict__ tb,
    const unsigned* __restrict__ enc_ws,
    const float* __restrict__ W0,
    const float* __restrict__ W1,
    const float* __restrict__ W2,
    float* __restrict__ out,
    int n, DenseParams P)
{
    __shared__ float tst[768];
    __shared__ __align__(16) unsigned char slabs[4 * 64 * 80];
    const int tid = threadIdx.x;
    const int i0 = blockIdx.x * 256;

    tst[tid]       = __builtin_nontemporal_load(texc + 3 * i0 + tid);
    tst[tid + 256] = __builtin_nontemporal_load(texc + 3 * i0 + tid + 256);
    tst[tid + 512] = __builtin_nontemporal_load(texc + 3 * i0 + tid + 512);
    __syncthreads();

    const int i = i0 + tid;
    unsigned dd[16];

    // Hashed feature streams: issued now, consumed only at slab-store time.
#pragma unroll
    for (int l = 0; l < N_HASH; ++l)
        dd[N_DENSE + l] = __builtin_nontemporal_load(enc_ws + (size_t)l * n + i);

    const float tx = tst[3 * tid + 0], ty = tst[3 * tid + 1], tz = tst[3 * tid + 2];

    // Per-level address/weight precompute (all 5 levels).
    float wyzd[N_DENSE][4], wx0d[N_DENSE], wx1d[N_DENSE];
    unsigned iAd[N_DENSE][4], sAd[N_DENSE][4];
#pragma unroll
    for (int l = 0; l < N_DENSE; ++l) {
        const float s = P.scale[l];
        const unsigned res = P.res[l];
        const unsigned res2 = res * res;
        const float px = tx * s + 0.5f, py = ty * s + 0.5f, pz = tz * s + 0.5f;
        const float gx = floorf(px), gy = floorf(py), gz = floorf(pz);
        const float wx = px - gx, wy = py - gy, wz = pz - gz;
        const unsigned x0 = (unsigned)gx, y0 = (unsigned)gy, z0 = (unsigned)gz;
        wx0d[l] = 1.f - wx; wx1d[l] = wx;
        wyzd[l][0] = (1.f - wy) * (1.f - wz);
        wyzd[l][1] = wy * (1.f - wz);
        wyzd[l][2] = (1.f - wy) * wz;
        wyzd[l][3] = wy * wz;
        const unsigned b0 = y0 * res + z0 * res2;
#pragma unroll
        for (int c = 0; c < 4; ++c) {
            const unsigned idx0 = x0 + b0 + (c & 1u) * res + (c >> 1) * res2;
            iAd[l][c] = idx0 & ~1u;
            sAd[l][c] = idx0 & 1u;
        }
    }

    // Chunked loads: {0,1} then {2,3,4}; within a chunk all loads issue first.
#pragma unroll
    for (int ch = 0; ch < 2; ++ch) {
        const int l0 = ch ? 2 : 0, nl = ch ? 3 : 2;
        u32x2 gA[3][4], gB[3][4];
#pragma unroll
        for (int k = 0; k < 3; ++k) {
            if (k >= nl) break;
            const unsigned* tbl = tb + ((size_t)(l0 + k) << 19);
#pragma unroll
            for (int c = 0; c < 4; ++c) {
                gA[k][c] = *(const u32x2*)(tbl + iAd[l0 + k][c]);
                gB[k][c] = *(const u32x2*)(tbl + ((iAd[l0 + k][c] + sAd[l0 + k][c] * 2u) & (TMASK & ~1u)));
            }
        }
#pragma unroll
        for (int k = 0; k < 3; ++k) {
            if (k >= nl) break;
            const int l = l0 + k;
            float f0 = 0.f, f1 = 0.f;
#pragma unroll
            for (int c = 0; c < 4; ++c) {
                const unsigned ea = sAd[l][c] ? gA[k][c].y : gA[k][c].x;
                const unsigned eb = sAd[l][c] ? gB[k][c].x : gB[k][c].y;
                f0 += wyzd[l][c] * (wx0d[l] * bflo(ea) + wx1d[l] * bflo(eb));
                f1 += wyzd[l][c] * (wx0d[l] * bfhi(ea) + wx1d[l] * bfhi(eb));
            }
            dd[l] = bf16_bits(f0) | (bf16_bits(f1) << 16);
        }
    }

    // ---- MFMA MLP (verified R4/R5) ----
    const int lane = tid & 63;
    const int wv = tid >> 6;
    const int c16 = lane & 15, q = lane >> 4;
    unsigned char* slabB = slabs + wv * (64 * 80);
    unsigned* slab = (unsigned*)slabB;   // row stride 20 dwords (80 B)

    *(u32x4*)(slabB + lane * 80 +  0) = (u32x4){ dd[0],  dd[1],  dd[2],  dd[3]  };
    *(u32x4*)(slabB + lane * 80 + 16) = (u32x4){ dd[4],  dd[5],  dd[6],  dd[7]  };
    *(u32x4*)(slabB + lane * 80 + 32) = (u32x4){ dd[8],  dd[9],  dd[10], dd[11] };
    *(u32x4*)(slabB + lane * 80 + 48) = (u32x4){ dd[12], dd[13], dd[14], dd[15] };

    const s16x8 b00 = packW8(W0 + c16 * 32 + 8 * q);
    const s16x8 b01 = packW8(W0 + (16 + c16) * 32 + 8 * q);
    const s16x8 b10 = packW8sig(W1 + c16 * 32, q);
    const s16x8 b11 = packW8sig(W1 + (16 + c16) * 32, q);
    const f32x4 zero4 = { 0.f, 0.f, 0.f, 0.f };

    f32x4 d0[4][2];
#pragma unroll
    for (int t = 0; t < 4; ++t) {
        const s16x8 a = *(const s16x8*)(slabB + (16 * t + c16) * 80 + 16 * q);
        d0[t][0] = __builtin_amdgcn_mfma_f32_16x16x32_bf16(a, b00, zero4, 0, 0, 0);
        d0[t][1] = __builtin_amdgcn_mfma_f32_16x16x32_bf16(a, b01, zero4, 0, 0, 0);
    }
#pragma unroll
    for (int t = 0; t < 4; ++t)
#pragma unroll
        for (int r = 0; r < 4; ++r) {
            const unsigned pk = bf16_bits(fmaxf(d0[t][0][r], 0.f)) |
                                (bf16_bits(fmaxf(d0[t][1][r], 0.f)) << 16);
            slab[(16 * t + 4 * q + r) * 20 + c16] = pk;
        }

    f32x4 d1[4][2];
#pragma unroll
    for (int t = 0; t < 4; ++t) {
        const s16x8 a = *(const s16x8*)(slabB + (16 * t + c16) * 80 + 16 * q);
        d1[t][0] = __builtin_amdgcn_mfma_f32_16x16x32_bf16(a, b10, zero4, 0, 0, 0);
        d1[t][1] = __builtin_amdgcn_mfma_f32_16x16x32_bf16(a, b11, zero4, 0, 0, 0);
    }
#pragma unroll
    for (int t = 0; t < 4; ++t)
#pragma unroll
        for (int r = 0; r < 4; ++r) {
            const unsigned pk = bf16_bits(fmaxf(d1[t][0][r], 0.f)) |
                                (bf16_bits(fmaxf(d1[t][1][r], 0.f)) << 16);
            slab[(16 * t + 4 * q + r) * 20 + c16] = pk;
        }

    float z0 = 0.f, z1 = 0.f, z2 = 0.f;
#pragma unroll
    for (int d = 0; d < 16; ++d) {
        const unsigned v = slab[lane * 20 + d];
        const float a0 = bflo(v), a1 = bfhi(v);
        z0 = fmaf(a0, W2[0 * 32 + d], fmaf(a1, W2[0 * 32 + 16 + d], z0));
        z1 = fmaf(a0, W2[1 * 32 + d], fmaf(a1, W2[1 * 32 + 16 + d], z1));
        z2 = fmaf(a0, W2[2 * 32 + d], fmaf(a1, W2[2 * 32 + 16 + d], z2));
    }
    out[3 * i + 0] = 1.f / (1.f + __expf(-z0));
    out[3 * i + 1] = 1.f / (1.f + __expf(-z1));
    out[3 * i + 2] = 1.f / (1.f + __expf(-z2));
}

// ---------------------------------------------------------------------------
// Fallback: monolithic kernel.
// ---------------------------------------------------------------------------
__global__ __launch_bounds__(256) void mono_kernel(
    const float* __restrict__ texc, const float* __restrict__ table,
    const float* __restrict__ W0, const float* __restrict__ W1,
    const float* __restrict__ W2, float* __restrict__ out, int n, AllParams p)
{
    int i = blockIdx.x * 256 + threadIdx.x;
    if (i >= n) return;
    const float tx = texc[3 * i], ty = texc[3 * i + 1], tz = texc[3 * i + 2];
    float enc[2 * NUM_LEVELS];
#pragma unroll
    for (int l = 0; l < NUM_LEVELS; ++l) {
        const float s = p.scale[l];
        const unsigned res = p.res[l];
        const float px = tx * s + 0.5f, py = ty * s + 0.5f, pz = tz * s + 0.5f;
        const float gx = floorf(px), gy = floorf(py), gz = floorf(pz);
        const float wx = px - gx, wy = py - gy, wz = pz - gz;
        const unsigned x0 = (unsigned)gx, y0 = (unsigned)gy, z0 = (unsigned)gz;
        const float2* tbl = (const float2*)(table + ((size_t)l << 20));
        float f0 = 0.f, f1 = 0.f;
#pragma unroll
        for (int c = 0; c < 8; ++c) {
            const unsigned dx = c & 1u, dy = (c >> 1) & 1u, dz = (c >> 2) & 1u;
            const unsigned xi = x0 + dx, yi = y0 + dy, zi = z0 + dz;
            unsigned idx;
            if (l < N_DENSE) idx = xi + yi * res + zi * res * res;
            else idx = (xi ^ (yi * 2654435761u) ^ (zi * 805459861u)) & TMASK;
            const float2 g = tbl[idx];
            const float w = (dx ? wx : 1.f - wx) * (dy ? wy : 1.f - wy) *
                            (dz ? wz : 1.f - wz);
            f0 = fmaf(w, g.x, f0);
            f1 = fmaf(w, g.y, f1);
        }
        enc[2 * l] = f0;
        enc[2 * l + 1] = f1;
    }
    float h1[32];
#pragma unroll
    for (int j = 0; j < 32; ++j) {
        float acc = 0.f;
#pragma unroll
        for (int k = 0; k < 32; ++k) acc = fmaf(enc[k], W0[j * 32 + k], acc);
        h1[j] = fmaxf(acc, 0.f);
    }
    float h2[32];
#pragma unroll
    for (int j = 0; j < 32; ++j) {
        float acc = 0.f;
#pragma unroll
        for (int k = 0; k < 32; ++k) acc = fmaf(h1[k], W1[j * 32 + k], acc);
        h2[j] = fmaxf(acc, 0.f);
    }
#pragma unroll
    for (int j = 0; j < 3; ++j) {
        float acc = 0.f;
#pragma unroll
        for (int k = 0; k < 32; ++k) acc = fmaf(h2[k], W2[j * 32 + k], acc);
        out[3 * i + j] = 1.f / (1.f + __expf(-acc));
    }
}

extern "C" void kernel_launch(void* const* d_in, const int* in_sizes, int n_in,
                              void* d_out, int out_size, void* d_ws, size_t ws_size,
                              hipStream_t stream) {
    const float* texc  = (const float*)d_in[0];
    const float* table = (const float*)d_in[1];
    const float* W0    = (const float*)d_in[2];
    const float* W1    = (const float*)d_in[3];
    const float* W2    = (const float*)d_in[4];
    float* out = (float*)d_out;

    const int n = in_sizes[0] / 3;

    AllParams ap;
    const double log2pls = log(4096.0 / 16.0) / 15.0 / log(2.0);
    for (int l = 0; l < NUM_LEVELS; ++l) {
        const double sc = exp2((double)l * log2pls) * 16.0 - 1.0;
        ap.scale[l] = (float)sc;
        ap.res[l] = (unsigned)(ceil(sc) + 1.0);
    }

    const size_t enc_b = (size_t)N_HASH * (size_t)n * 4u;
    const size_t tbl_b = (size_t)NUM_LEVELS * TABLE_SIZE * 4u;   // 32 MiB

    if ((n % 512) == 0 && ws_size >= tbl_b + enc_b) {
        HashParams hp;
        for (int l = 0; l < N_HASH; ++l) hp.scale[l] = ap.scale[l + N_DENSE];
        DenseParams dp;
        for (int l = 0; l < N_DENSE; ++l) { dp.scale[l] = ap.scale[l]; dp.res[l] = ap.res[l]; }

        unsigned* bt = (unsigned*)d_ws;
        unsigned* enc_ws = bt + (size_t)NUM_LEVELS * TABLE_SIZE;
        const int n2 = NUM_LEVELS * TABLE_SIZE / 2;
        cvt_table_kernel<<<(n2 + 255) / 256, 256, 0, stream>>>(
            (const f32x4*)table, (u32x2*)bt, n2);

        const int B2 = n / 512;
        hashed_all_kernel<<<B2 * N_HASH, 256, 0, stream>>>(
            texc, bt, enc_ws, n, B2, hp);
        dense_mlp_kernel<<<n / 256, 256, 0, stream>>>(
            texc, bt, enc_ws, W0, W1, W2, out, n, dp);
    } else {
        const int blocks = (n + 255) / 256;
        mono_kernel<<<blocks, 256, 0, stream>>>(texc, table, W0, W1, W2, out, n, ap);
    }
}